// Round 18
// baseline (217.021 us; speedup 1.0000x reference)
//
#include <hip/hip_runtime.h>

// MultiHeadAttention: B=4, L=2048, H=16, D_MODEL=1024, D_K=D_V=64
// Round 18: proj_fused = 256x256 tile, BK=32, 2-ring 64KB (2 blocks/CU),
// r12's verified schedule (2-tile lead, counted vmcnt(4), stage-after-bar2),
// r11/r13-verified swizzle + grid map + epilogue. All 384 blocks resident.
// attn/cvt/gemm_out = r17 exact (best total 181.1us).

typedef __bf16 bf16;
typedef __attribute__((ext_vector_type(8))) __bf16 bf16x8;
typedef __attribute__((ext_vector_type(4))) __bf16 bf16x4;
typedef __attribute__((ext_vector_type(4))) float f32x4;
typedef __attribute__((ext_vector_type(16))) float f32x16;

// ---------------- fused fp32 -> bf16 convert: Q,K,V + 4 weights ----------------
__global__ __launch_bounds__(256) void cvt_all(
    const float* __restrict__ Q, const float* __restrict__ K, const float* __restrict__ V,
    const float* __restrict__ Wq, const float* __restrict__ Wk,
    const float* __restrict__ Wv, const float* __restrict__ Wo,
    bf16* __restrict__ ws)
{
    int bid = blockIdx.x;
    const float* src;
    bf16* dst;
    int lb;
    if (bid < 4096)       { src = Q;  dst = ws;             lb = bid; }
    else if (bid < 8192)  { src = K;  dst = ws + 8388608;   lb = bid - 4096; }
    else if (bid < 12288) { src = V;  dst = ws + 16777216;  lb = bid - 8192; }
    else if (bid < 12800) { src = Wq; dst = ws + 25165824;  lb = bid - 12288; }
    else if (bid < 13312) { src = Wk; dst = ws + 26214400;  lb = bid - 12800; }
    else if (bid < 13824) { src = Wv; dst = ws + 27262976;  lb = bid - 13312; }
    else                  { src = Wo; dst = ws + 28311552;  lb = bid - 13824; }
    size_t i = ((size_t)lb * 256 + threadIdx.x) * 8;
    f32x4 a = *(const f32x4*)(src + i);
    f32x4 b = *(const f32x4*)(src + i + 4);
    bf16x8 o;
    o[0] = (bf16)a[0]; o[1] = (bf16)a[1]; o[2] = (bf16)a[2]; o[3] = (bf16)a[3];
    o[4] = (bf16)b[0]; o[5] = (bf16)b[1]; o[6] = (bf16)b[2]; o[7] = (bf16)b[3];
    *(bf16x8*)(dst + i) = o;
}

__device__ inline void gld_lds16(const void* g, void* l) {
    __builtin_amdgcn_global_load_lds((const __attribute__((address_space(1))) void*)g,
                                     (__attribute__((address_space(3))) void*)l, 16, 0, 0);
}

// ---------------- fused Q/K/V projection: 256x256, BK=32, 2-ring, r12 schedule -------
// grid 384 flat (r11 map: XCD owns (z, m-pair) chunks, 3MB L2 working set).
// LDS [256][32] per matrix per buf; slot s at row r holds global slot s^((r>>1)&3)
// (r11/r13-verified 0-conflict). Schedule per K-tile kt (buf=kt&1):
//   vmcnt(4) [tile kt landed; kt+1 stays in flight] -> bar -> ds_read -> MFMA
//   -> bar2 [all waves' reads of buf done] -> stage kt+2 into buf (2-tile lead).
__global__ __launch_bounds__(512, 2) void proj_fused(
    const bf16* __restrict__ Xq, const bf16* __restrict__ Xk, const bf16* __restrict__ Xv,
    const bf16* __restrict__ Wqb, const bf16* __restrict__ Wkb, const bf16* __restrict__ Wvb,
    const float* __restrict__ bq, const float* __restrict__ bk, const float* __restrict__ bv,
    bf16* __restrict__ qw, bf16* __restrict__ kw, bf16* __restrict__ vtw)
{
    __shared__ bf16 lA[2][8192];
    __shared__ bf16 lB[2][8192];

    const int bid = blockIdx.x;
    const int xcd = bid & 7, idx = bid >> 3;       // idx 0..47
    const int chunk = idx >> 3, within = idx & 7;  // chunk 0..5
    const int gc = xcd * 6 + chunk;                // 0..47 (bijective)
    const int z  = gc >> 4;
    const int mp = gc & 15;
    const int m0 = (mp * 2 + (within >> 2)) * 256;
    const int n0 = (within & 3) * 256;

    const bf16*  A    = z == 0 ? Xq  : (z == 1 ? Xk  : Xv);
    const bf16*  W    = z == 0 ? Wqb : (z == 1 ? Wkb : Wvb);
    const float* bias = z == 0 ? bq  : (z == 1 ? bk  : bv);
    bf16*        out  = z == 0 ? qw  : (z == 1 ? kw  : vtw);
    const float scale = z == 0 ? 0.18033688011112042f : 1.0f;  // (1/8)*log2(e)

    const int tid  = threadIdx.x;
    const int wave = tid >> 6, lane = tid & 63;
    const int c = lane & 15, g = lane >> 4;
    const int wm = wave >> 2, wn = wave & 3;       // 2M x 4N, wave tile 128x64

    const int srow = lane >> 2;                              // 0..15
    const int scol = ((lane & 3) ^ ((lane >> 3) & 3)) * 8;   // pre-swizzled src slot
    const int rsw  = (g ^ ((c >> 1) & 3)) * 8;               // swizzled read slot

    f32x4 acc[8][4] = {};

#define SAB(kt_, bb)                                                            \
    {                                                                           \
        _Pragma("unroll")                                                       \
        for (int j = 0; j < 2; ++j) {                                           \
            gld_lds16(A + (size_t)(m0 + j * 128 + wave * 16 + srow) * 1024 +    \
                          (kt_) * 32 + scol,                                    \
                      &lA[bb][j * 4096 + wave * 512]);                          \
            gld_lds16(W + (size_t)(n0 + j * 128 + wave * 16 + srow) * 1024 +    \
                          (kt_) * 32 + scol,                                    \
                      &lB[bb][j * 4096 + wave * 512]);                          \
        }                                                                       \
    }

    SAB(0, 0);
    SAB(1, 1);

    for (int kt = 0; kt < 32; ++kt) {
        const int buf = kt & 1;
        if (kt < 31) {
            asm volatile("s_waitcnt vmcnt(4)" ::: "memory");   // tile kt landed
        } else {
            asm volatile("s_waitcnt vmcnt(0)" ::: "memory");
        }
        __builtin_amdgcn_s_barrier();
        asm volatile("" ::: "memory");

        bf16x8 af[8], bfr[4];
#pragma unroll
        for (int m = 0; m < 8; ++m)
            af[m] = *(const bf16x8*)&lA[buf][(wm * 128 + m * 16 + c) * 32 + rsw];
#pragma unroll
        for (int n = 0; n < 4; ++n)
            bfr[n] = *(const bf16x8*)&lB[buf][(wn * 64 + n * 16 + c) * 32 + rsw];

#pragma unroll
        for (int m = 0; m < 8; ++m)
#pragma unroll
            for (int n = 0; n < 4; ++n)
                acc[m][n] = __builtin_amdgcn_mfma_f32_16x16x32_bf16(af[m], bfr[n], acc[m][n], 0, 0, 0);

        asm volatile("" ::: "memory");
        __builtin_amdgcn_s_barrier();
        asm volatile("" ::: "memory");
        if (kt + 2 < 32) SAB(kt + 2, buf);     // overwrite safe: all reads of buf done
    }
#undef SAB

#pragma unroll
    for (int m = 0; m < 8; ++m) {
#pragma unroll
        for (int n = 0; n < 4; ++n) {
            int col  = n0 + wn * 64 + n * 16 + c;
            float bb = bias[col];
#pragma unroll
            for (int r = 0; r < 4; ++r) {
                int row = m0 + wm * 128 + m * 16 + 4 * g + r;
                float v = (acc[m][n][r] + bb) * scale;
                int b = row >> 11, l = row & 2047, hh = col >> 6, d = col & 63;
                size_t base = (size_t)(b * 16 + hh) * 131072;
                if (z < 2) {
                    out[base + (l >> 5) * 2048 + (d >> 4) * 512 +
                        ((d >> 3) & 1) * 256 + (l & 31) * 8 + (d & 7)] = (bf16)v;
                } else {
                    out[base + (l >> 5) * 2048 + (d >> 5) * 1024 +
                        ((l >> 4) & 1) * 512 + ((l >> 3) & 1) * 256 +
                        (d & 31) * 8 + (l & 7)] = (bf16)v;
                }
            }
        }
    }
}

// ---------------- output projection GEMM (r12: BK=64, 2-ring, swizzled, fp32 out) -----
__global__ __launch_bounds__(256) void gemm_out(
    const bf16* __restrict__ A, const bf16* __restrict__ W,
    const float* __restrict__ bias, float* __restrict__ out)
{
    __shared__ bf16 lA[2][8192];
    __shared__ bf16 lB[2][8192];
    const int tid  = threadIdx.x;
    const int wave = tid >> 6, lane = tid & 63;
    const int c = lane & 15, g = lane >> 4;

    const int oid = blockIdx.y * 8 + blockIdx.x;
    const int nid = (oid & 7) * 64 + (oid >> 3);
    const int m0 = (nid >> 3) * 128, n0 = (nid & 7) * 128;

    const int wr = wave >> 1, wc = wave & 1;
    const int srow  = lane >> 3;
    const int scol8 = ((lane & 7) ^ srow) * 8;
    const int c7 = c & 7;

    f32x4 acc[4][4] = {};

#define OSTAGE(kt_, bb)                                                         \
    {                                                                           \
        _Pragma("unroll")                                                       \
        for (int i = 0; i < 4; ++i) {                                           \
            int ca = wave * 4 + i;                                              \
            int arow = ca * 8 + srow;                                           \
            gld_lds16(A + (size_t)(m0 + arow) * 1024 + (kt_) * 64 + scol8,      \
                      &lA[bb][ca * 512]);                                       \
            gld_lds16(W + (size_t)(n0 + arow) * 1024 + (kt_) * 64 + scol8,      \
                      &lB[bb][ca * 512]);                                       \
        }                                                                       \
    }

    OSTAGE(0, 0);
    OSTAGE(1, 1);

    for (int kt = 0; kt < 16; ++kt) {
        const int buf = kt & 1;
        if (kt < 15) {
            asm volatile("s_waitcnt vmcnt(8)" ::: "memory");
        } else {
            asm volatile("s_waitcnt vmcnt(0)" ::: "memory");
        }
        __builtin_amdgcn_s_barrier();
        asm volatile("" ::: "memory");

#pragma unroll
        for (int ks = 0; ks < 2; ++ks) {
            bf16x8 af[4], bfr[4];
#pragma unroll
            for (int m = 0; m < 4; ++m) {
                int r = wr * 64 + m * 16 + c;
                af[m] = *(const bf16x8*)&lA[buf][r * 64 + (((ks * 4 + g) ^ c7) * 8)];
            }
#pragma unroll
            for (int n = 0; n < 4; ++n) {
                int r = wc * 64 + n * 16 + c;
                bfr[n] = *(const bf16x8*)&lB[buf][r * 64 + (((ks * 4 + g) ^ c7) * 8)];
            }
#pragma unroll
            for (int m = 0; m < 4; ++m)
#pragma unroll
                for (int n = 0; n < 4; ++n)
                    acc[m][n] = __builtin_amdgcn_mfma_f32_16x16x32_bf16(af[m], bfr[n], acc[m][n], 0, 0, 0);
        }

        asm volatile("" ::: "memory");
        __builtin_amdgcn_s_barrier();
        asm volatile("" ::: "memory");
        if (kt + 2 < 16) OSTAGE(kt + 2, buf);
    }
#undef OSTAGE

#pragma unroll
    for (int m = 0; m < 4; ++m) {
#pragma unroll
        for (int n = 0; n < 4; ++n) {
            int col  = n0 + wc * 64 + n * 16 + c;
            float bb = bias[col];
#pragma unroll
            for (int r = 0; r < 4; ++r) {
                int row = m0 + wr * 64 + m * 16 + 4 * g + r;
                out[(size_t)row * 1024 + col] = acc[m][n][r] + bb;
            }
        }
    }
}

// ---------------- helpers for attn ----------------
__device__ inline unsigned cvtpk(float lo, float hi) {
    unsigned r;
    asm("v_cvt_pk_bf16_f32 %0, %1, %2" : "=v"(r) : "v"(lo), "v"(hi));
    return r;
}
__device__ inline void pswap(unsigned &a, unsigned &b) {
    asm("v_permlane32_swap_b32 %0, %1" : "+v"(a), "+v"(b));
}

// ---------------- flash attention: 8-wave blocks, 3-ring, one barrier/tile ------------
// r17 exact (setprio-free).
__global__ __launch_bounds__(512) void attn_kernel(
    const bf16* __restrict__ q, const bf16* __restrict__ k,
    const bf16* __restrict__ vt, bf16* __restrict__ O)
{
    __shared__ bf16 lkv[3][4096];   // [ring][K 2048 | V 2048]
    const int tid  = threadIdx.x;
    const int wave = tid >> 6, lane = tid & 63;
    const int l31 = lane & 31, hi = lane >> 5;
    const int orig = blockIdx.x;
    const int swz  = (orig & 7) * 64 + (orig >> 3);  // bijective (512 % 8 == 0)
    const int bh = swz >> 3;
    const int q0 = (swz & 7) * 256 + wave * 32;
    const int laneoff = hi * 256 + l31 * 8;

    const bf16* qb = q  + (size_t)bh * 131072 + (q0 >> 5) * 2048 + laneoff;
    const bf16* kb = k  + (size_t)bh * 131072;
    const bf16* vb = vt + (size_t)bh * 131072;

    bf16x8 qf0 = *(const bf16x8*)(qb);
    bf16x8 qf1 = *(const bf16x8*)(qb + 512);
    bf16x8 qf2 = *(const bf16x8*)(qb + 1024);
    bf16x8 qf3 = *(const bf16x8*)(qb + 1536);

    const bf16* sg = (wave < 4) ? (kb + wave * 512 + lane * 8)
                                : (vb + (wave - 4) * 512 + lane * 8);
    const int   sl = (wave < 4) ? wave * 512 : 2048 + (wave - 4) * 512;

    f32x16 acc0 = {}, acc1 = {};
    float lsum = 0.f;

    gld_lds16(sg,        &lkv[0][sl]);
    gld_lds16(sg + 2048, &lkv[1][sl]);

    int cur = 0;
    for (int t = 0; t < 64; ++t) {
        if (t < 63) {
            asm volatile("s_waitcnt vmcnt(1)" ::: "memory");  // S(t) landed
        } else {
            asm volatile("s_waitcnt vmcnt(0)" ::: "memory");
        }
        __syncthreads();
        if (t + 2 < 64) {
            int nb = cur + 2; if (nb >= 3) nb -= 3;
            gld_lds16(sg + (size_t)(t + 2) * 2048, &lkv[nb][sl]);
        }

        const bf16* kl = &lkv[cur][laneoff];
        const bf16* vl = &lkv[cur][2048 + laneoff];
        bf16x8 kf0  = *(const bf16x8*)(kl);
        bf16x8 kf1  = *(const bf16x8*)(kl + 512);
        bf16x8 kf2  = *(const bf16x8*)(kl + 1024);
        bf16x8 kf3  = *(const bf16x8*)(kl + 1536);
        bf16x8 vf00 = *(const bf16x8*)(vl);
        bf16x8 vf01 = *(const bf16x8*)(vl + 512);
        bf16x8 vf10 = *(const bf16x8*)(vl + 1024);
        bf16x8 vf11 = *(const bf16x8*)(vl + 1536);

        f32x16 st = {};
        st = __builtin_amdgcn_mfma_f32_32x32x16_bf16(kf0, qf0, st, 0, 0, 0);
        st = __builtin_amdgcn_mfma_f32_32x32x16_bf16(kf1, qf1, st, 0, 0, 0);
        st = __builtin_amdgcn_mfma_f32_32x32x16_bf16(kf2, qf2, st, 0, 0, 0);
        st = __builtin_amdgcn_mfma_f32_32x32x16_bf16(kf3, qf3, st, 0, 0, 0);

#pragma unroll
        for (int r = 0; r < 16; ++r) st[r] = __builtin_amdgcn_exp2f(st[r]);

        float s0 = (st[0] + st[1]) + (st[2] + st[3]);
        float s1 = (st[4] + st[5]) + (st[6] + st[7]);
        float s2 = (st[8] + st[9]) + (st[10] + st[11]);
        float s3 = (st[12] + st[13]) + (st[14] + st[15]);
        lsum += (s0 + s1) + (s2 + s3);

        unsigned u01 = cvtpk(st[0],  st[1]),  u23 = cvtpk(st[2],  st[3]);
        unsigned u45 = cvtpk(st[4],  st[5]),  u67 = cvtpk(st[6],  st[7]);
        unsigned u89 = cvtpk(st[8],  st[9]),  uAB = cvtpk(st[10], st[11]);
        unsigned uCD = cvtpk(st[12], st[13]), uEF = cvtpk(st[14], st[15]);
        pswap(u01, u45); pswap(u23, u67);
        pswap(u89, uCD); pswap(uAB, uEF);
        union { unsigned u[4]; bf16x8 v; } pf0, pf1;
        pf0.u[0] = u01; pf0.u[1] = u23; pf0.u[2] = u45; pf0.u[3] = u67;
        pf1.u[0] = u89; pf1.u[1] = uAB; pf1.u[2] = uCD; pf1.u[3] = uEF;

        acc0 = __builtin_amdgcn_mfma_f32_32x32x16_bf16(vf00, pf0.v, acc0, 0, 0, 0);
        acc1 = __builtin_amdgcn_mfma_f32_32x32x16_bf16(vf10, pf0.v, acc1, 0, 0, 0);
        acc0 = __builtin_amdgcn_mfma_f32_32x32x16_bf16(vf01, pf1.v, acc0, 0, 0, 0);
        acc1 = __builtin_amdgcn_mfma_f32_32x32x16_bf16(vf11, pf1.v, acc1, 0, 0, 0);

        cur = (cur == 2) ? 0 : cur + 1;
    }

    lsum += __shfl_xor(lsum, 32);
    float inv = 1.0f / lsum;
    int qg = q0 + l31;
    bf16* ob = O + ((size_t)(bh >> 4) * 2048 + qg) * 1024 + (size_t)(bh & 15) * 64;
#pragma unroll
    for (int rg = 0; rg < 4; ++rg) {
        bf16x4 w0, w1;
#pragma unroll
        for (int i = 0; i < 4; ++i) {
            w0[i] = (bf16)(acc0[rg * 4 + i] * inv);
            w1[i] = (bf16)(acc1[rg * 4 + i] * inv);
        }
        *(bf16x4*)(ob + 8 * rg + 4 * hi)      = w0;
        *(bf16x4*)(ob + 32 + 8 * rg + 4 * hi) = w1;
    }
}

extern "C" void kernel_launch(void* const* d_in, const int* in_sizes, int n_in,
                              void* d_out, int out_size, void* d_ws, size_t ws_size,
                              hipStream_t stream) {
    (void)in_sizes; (void)n_in; (void)out_size; (void)ws_size;
    // setup_inputs order: V, K, Q, Wv, bv, Wk, bk, Wq, bq, Wo, bo
    const float* V  = (const float*)d_in[0];
    const float* K  = (const float*)d_in[1];
    const float* Q  = (const float*)d_in[2];
    const float* Wv = (const float*)d_in[3];
    const float* bv = (const float*)d_in[4];
    const float* Wk = (const float*)d_in[5];
    const float* bk = (const float*)d_in[6];
    const float* Wq = (const float*)d_in[7];
    const float* bq = (const float*)d_in[8];
    const float* Wo = (const float*)d_in[9];
    const float* bo = (const float*)d_in[10];

    char* ws = (char*)d_ws;
    const size_t MB = 1ull << 20;
    bf16* Xq  = (bf16*)(ws + 0);        // dead after proj -> reused as O
    bf16* Xk  = (bf16*)(ws + 16 * MB);
    bf16* Xv  = (bf16*)(ws + 32 * MB);
    bf16* Wqb = (bf16*)(ws + 48 * MB);
    bf16* Wkb = (bf16*)(ws + 50 * MB);
    bf16* Wvb = (bf16*)(ws + 52 * MB);
    bf16* Wob = (bf16*)(ws + 54 * MB);
    bf16* qw  = (bf16*)(ws + 56 * MB);
    bf16* kw  = (bf16*)(ws + 72 * MB);
    bf16* vtw = (bf16*)(ws + 88 * MB);
    bf16* Ow  = (bf16*)(ws + 0);

    cvt_all<<<14336, 256, 0, stream>>>(Q, K, V, Wq, Wk, Wv, Wo, (bf16*)ws);

    proj_fused<<<384, 512, 0, stream>>>(
        Xq, Xk, Xv, Wqb, Wkb, Wvb, bq, bk, bv, qw, kw, vtw);

    attn_kernel<<<512, 512, 0, stream>>>(qw, kw, vtw, Ow);

    gemm_out<<<dim3(8, 64), 256, 0, stream>>>(Ow, Wob, bo, (float*)d_out);
}

// Round 19
// 181.119 us; speedup vs baseline: 1.1982x; 1.1982x over previous
//
#include <hip/hip_runtime.h>

// MultiHeadAttention: B=4, L=2048, H=16, D_MODEL=1024, D_K=D_V=64
// Round 19: restore r17 exact — best measured total (181.1us).
// proj 128²/BK=64/2-ring (93us, 0 conflicts), attn 3-ring 1-barrier
// setprio-free (~53us), fused cvt, gemm_out 128²/BK=64.
// 256²-family refuted 4x (r10/r11/r13/r18); (512,N) min-waves clause
// refuted (r15: VGPR cap -> spill); pair-tile refuted (r16).

typedef __bf16 bf16;
typedef __attribute__((ext_vector_type(8))) __bf16 bf16x8;
typedef __attribute__((ext_vector_type(4))) __bf16 bf16x4;
typedef __attribute__((ext_vector_type(4))) float f32x4;
typedef __attribute__((ext_vector_type(16))) float f32x16;

// ---------------- fused fp32 -> bf16 convert: Q,K,V + 4 weights ----------------
__global__ __launch_bounds__(256) void cvt_all(
    const float* __restrict__ Q, const float* __restrict__ K, const float* __restrict__ V,
    const float* __restrict__ Wq, const float* __restrict__ Wk,
    const float* __restrict__ Wv, const float* __restrict__ Wo,
    bf16* __restrict__ ws)
{
    int bid = blockIdx.x;
    const float* src;
    bf16* dst;
    int lb;
    if (bid < 4096)       { src = Q;  dst = ws;             lb = bid; }
    else if (bid < 8192)  { src = K;  dst = ws + 8388608;   lb = bid - 4096; }
    else if (bid < 12288) { src = V;  dst = ws + 16777216;  lb = bid - 8192; }
    else if (bid < 12800) { src = Wq; dst = ws + 25165824;  lb = bid - 12288; }
    else if (bid < 13312) { src = Wk; dst = ws + 26214400;  lb = bid - 12800; }
    else if (bid < 13824) { src = Wv; dst = ws + 27262976;  lb = bid - 13312; }
    else                  { src = Wo; dst = ws + 28311552;  lb = bid - 13824; }
    size_t i = ((size_t)lb * 256 + threadIdx.x) * 8;
    f32x4 a = *(const f32x4*)(src + i);
    f32x4 b = *(const f32x4*)(src + i + 4);
    bf16x8 o;
    o[0] = (bf16)a[0]; o[1] = (bf16)a[1]; o[2] = (bf16)a[2]; o[3] = (bf16)a[3];
    o[4] = (bf16)b[0]; o[5] = (bf16)b[1]; o[6] = (bf16)b[2]; o[7] = (bf16)b[3];
    *(bf16x8*)(dst + i) = o;
}

__device__ inline void gld_lds16(const void* g, void* l) {
    __builtin_amdgcn_global_load_lds((const __attribute__((address_space(1))) void*)g,
                                     (__attribute__((address_space(3))) void*)l, 16, 0, 0);
}

// ---------------- fused Q/K/V projection (BK=64, 2-ring, row-XOR swizzle) -------------
__global__ __launch_bounds__(256) void proj_fused(
    const bf16* __restrict__ Xq, const bf16* __restrict__ Xk, const bf16* __restrict__ Xv,
    const bf16* __restrict__ Wqb, const bf16* __restrict__ Wkb, const bf16* __restrict__ Wvb,
    const float* __restrict__ bq, const float* __restrict__ bk, const float* __restrict__ bv,
    bf16* __restrict__ qw, bf16* __restrict__ kw, bf16* __restrict__ vtw)
{
    __shared__ bf16 lA[2][8192];
    __shared__ bf16 lB[2][8192];
    const int z = blockIdx.z;
    const bf16*  A    = z == 0 ? Xq  : (z == 1 ? Xk  : Xv);
    const bf16*  W    = z == 0 ? Wqb : (z == 1 ? Wkb : Wvb);
    const float* bias = z == 0 ? bq  : (z == 1 ? bk  : bv);
    bf16*        out  = z == 0 ? qw  : (z == 1 ? kw  : vtw);
    const float scale = z == 0 ? 0.18033688011112042f : 1.0f;  // (1/8)*log2(e)

    const int tid  = threadIdx.x;
    const int wave = tid >> 6, lane = tid & 63;
    const int c = lane & 15, g = lane >> 4;

    const int oid = blockIdx.y * 8 + blockIdx.x;
    const int nid = (oid & 7) * 64 + (oid >> 3);
    const int m0 = (nid >> 3) * 128, n0 = (nid & 7) * 128;

    const int wr = wave >> 1, wc = wave & 1;
    const int srow  = lane >> 3;
    const int scol8 = ((lane & 7) ^ srow) * 8;
    const int c7 = c & 7;

    f32x4 acc[4][4] = {};

#define PSTAGE(kt_, bb)                                                         \
    {                                                                           \
        _Pragma("unroll")                                                       \
        for (int i = 0; i < 4; ++i) {                                           \
            int ca = wave * 4 + i;                                              \
            int arow = ca * 8 + srow;                                           \
            gld_lds16(A + (size_t)(m0 + arow) * 1024 + (kt_) * 64 + scol8,      \
                      &lA[bb][ca * 512]);                                       \
            gld_lds16(W + (size_t)(n0 + arow) * 1024 + (kt_) * 64 + scol8,      \
                      &lB[bb][ca * 512]);                                       \
        }                                                                       \
    }

    PSTAGE(0, 0);
    PSTAGE(1, 1);

    for (int kt = 0; kt < 16; ++kt) {
        const int buf = kt & 1;
        if (kt < 15) {
            asm volatile("s_waitcnt vmcnt(8)" ::: "memory");
        } else {
            asm volatile("s_waitcnt vmcnt(0)" ::: "memory");
        }
        __builtin_amdgcn_s_barrier();
        asm volatile("" ::: "memory");

#pragma unroll
        for (int ks = 0; ks < 2; ++ks) {
            bf16x8 af[4], bfr[4];
#pragma unroll
            for (int m = 0; m < 4; ++m) {
                int r = wr * 64 + m * 16 + c;
                af[m] = *(const bf16x8*)&lA[buf][r * 64 + (((ks * 4 + g) ^ c7) * 8)];
            }
#pragma unroll
            for (int n = 0; n < 4; ++n) {
                int r = wc * 64 + n * 16 + c;
                bfr[n] = *(const bf16x8*)&lB[buf][r * 64 + (((ks * 4 + g) ^ c7) * 8)];
            }
#pragma unroll
            for (int m = 0; m < 4; ++m)
#pragma unroll
                for (int n = 0; n < 4; ++n)
                    acc[m][n] = __builtin_amdgcn_mfma_f32_16x16x32_bf16(af[m], bfr[n], acc[m][n], 0, 0, 0);
        }

        asm volatile("" ::: "memory");
        __builtin_amdgcn_s_barrier();
        asm volatile("" ::: "memory");
        if (kt + 2 < 16) PSTAGE(kt + 2, buf);
    }
#undef PSTAGE

#pragma unroll
    for (int m = 0; m < 4; ++m) {
#pragma unroll
        for (int n = 0; n < 4; ++n) {
            int col  = n0 + wc * 64 + n * 16 + c;
            float bb = bias[col];
#pragma unroll
            for (int r = 0; r < 4; ++r) {
                int row = m0 + wr * 64 + m * 16 + 4 * g + r;
                float v = (acc[m][n][r] + bb) * scale;
                int b = row >> 11, l = row & 2047, hh = col >> 6, d = col & 63;
                size_t base = (size_t)(b * 16 + hh) * 131072;
                if (z < 2) {
                    out[base + (l >> 5) * 2048 + (d >> 4) * 512 +
                        ((d >> 3) & 1) * 256 + (l & 31) * 8 + (d & 7)] = (bf16)v;
                } else {
                    out[base + (l >> 5) * 2048 + (d >> 5) * 1024 +
                        ((l >> 4) & 1) * 512 + ((l >> 3) & 1) * 256 +
                        (d & 31) * 8 + (l & 7)] = (bf16)v;
                }
            }
        }
    }
}

// ---------------- output projection GEMM (BK=64, 2-ring, swizzled, fp32 out) ----------
__global__ __launch_bounds__(256) void gemm_out(
    const bf16* __restrict__ A, const bf16* __restrict__ W,
    const float* __restrict__ bias, float* __restrict__ out)
{
    __shared__ bf16 lA[2][8192];
    __shared__ bf16 lB[2][8192];
    const int tid  = threadIdx.x;
    const int wave = tid >> 6, lane = tid & 63;
    const int c = lane & 15, g = lane >> 4;

    const int oid = blockIdx.y * 8 + blockIdx.x;
    const int nid = (oid & 7) * 64 + (oid >> 3);
    const int m0 = (nid >> 3) * 128, n0 = (nid & 7) * 128;

    const int wr = wave >> 1, wc = wave & 1;
    const int srow  = lane >> 3;
    const int scol8 = ((lane & 7) ^ srow) * 8;
    const int c7 = c & 7;

    f32x4 acc[4][4] = {};

#define OSTAGE(kt_, bb)                                                         \
    {                                                                           \
        _Pragma("unroll")                                                       \
        for (int i = 0; i < 4; ++i) {                                           \
            int ca = wave * 4 + i;                                              \
            int arow = ca * 8 + srow;                                           \
            gld_lds16(A + (size_t)(m0 + arow) * 1024 + (kt_) * 64 + scol8,      \
                      &lA[bb][ca * 512]);                                       \
            gld_lds16(W + (size_t)(n0 + arow) * 1024 + (kt_) * 64 + scol8,      \
                      &lB[bb][ca * 512]);                                       \
        }                                                                       \
    }

    OSTAGE(0, 0);
    OSTAGE(1, 1);

    for (int kt = 0; kt < 16; ++kt) {
        const int buf = kt & 1;
        if (kt < 15) {
            asm volatile("s_waitcnt vmcnt(8)" ::: "memory");
        } else {
            asm volatile("s_waitcnt vmcnt(0)" ::: "memory");
        }
        __builtin_amdgcn_s_barrier();
        asm volatile("" ::: "memory");

#pragma unroll
        for (int ks = 0; ks < 2; ++ks) {
            bf16x8 af[4], bfr[4];
#pragma unroll
            for (int m = 0; m < 4; ++m) {
                int r = wr * 64 + m * 16 + c;
                af[m] = *(const bf16x8*)&lA[buf][r * 64 + (((ks * 4 + g) ^ c7) * 8)];
            }
#pragma unroll
            for (int n = 0; n < 4; ++n) {
                int r = wc * 64 + n * 16 + c;
                bfr[n] = *(const bf16x8*)&lB[buf][r * 64 + (((ks * 4 + g) ^ c7) * 8)];
            }
#pragma unroll
            for (int m = 0; m < 4; ++m)
#pragma unroll
                for (int n = 0; n < 4; ++n)
                    acc[m][n] = __builtin_amdgcn_mfma_f32_16x16x32_bf16(af[m], bfr[n], acc[m][n], 0, 0, 0);
        }

        asm volatile("" ::: "memory");
        __builtin_amdgcn_s_barrier();
        asm volatile("" ::: "memory");
        if (kt + 2 < 16) OSTAGE(kt + 2, buf);
    }
#undef OSTAGE

#pragma unroll
    for (int m = 0; m < 4; ++m) {
#pragma unroll
        for (int n = 0; n < 4; ++n) {
            int col  = n0 + wc * 64 + n * 16 + c;
            float bb = bias[col];
#pragma unroll
            for (int r = 0; r < 4; ++r) {
                int row = m0 + wr * 64 + m * 16 + 4 * g + r;
                out[(size_t)row * 1024 + col] = acc[m][n][r] + bb;
            }
        }
    }
}

// ---------------- helpers for attn ----------------
__device__ inline unsigned cvtpk(float lo, float hi) {
    unsigned r;
    asm("v_cvt_pk_bf16_f32 %0, %1, %2" : "=v"(r) : "v"(lo), "v"(hi));
    return r;
}
__device__ inline void pswap(unsigned &a, unsigned &b) {
    asm("v_permlane32_swap_b32 %0, %1" : "+v"(a), "+v"(b));
}

// ---------------- flash attention: 8-wave blocks, 3-ring, one barrier/tile ------------
__global__ __launch_bounds__(512) void attn_kernel(
    const bf16* __restrict__ q, const bf16* __restrict__ k,
    const bf16* __restrict__ vt, bf16* __restrict__ O)
{
    __shared__ bf16 lkv[3][4096];   // [ring][K 2048 | V 2048]
    const int tid  = threadIdx.x;
    const int wave = tid >> 6, lane = tid & 63;
    const int l31 = lane & 31, hi = lane >> 5;
    const int orig = blockIdx.x;
    const int swz  = (orig & 7) * 64 + (orig >> 3);  // bijective (512 % 8 == 0)
    const int bh = swz >> 3;
    const int q0 = (swz & 7) * 256 + wave * 32;
    const int laneoff = hi * 256 + l31 * 8;

    const bf16* qb = q  + (size_t)bh * 131072 + (q0 >> 5) * 2048 + laneoff;
    const bf16* kb = k  + (size_t)bh * 131072;
    const bf16* vb = vt + (size_t)bh * 131072;

    bf16x8 qf0 = *(const bf16x8*)(qb);
    bf16x8 qf1 = *(const bf16x8*)(qb + 512);
    bf16x8 qf2 = *(const bf16x8*)(qb + 1024);
    bf16x8 qf3 = *(const bf16x8*)(qb + 1536);

    const bf16* sg = (wave < 4) ? (kb + wave * 512 + lane * 8)
                                : (vb + (wave - 4) * 512 + lane * 8);
    const int   sl = (wave < 4) ? wave * 512 : 2048 + (wave - 4) * 512;

    f32x16 acc0 = {}, acc1 = {};
    float lsum = 0.f;

    gld_lds16(sg,        &lkv[0][sl]);
    gld_lds16(sg + 2048, &lkv[1][sl]);

    int cur = 0;
    for (int t = 0; t < 64; ++t) {
        if (t < 63) {
            asm volatile("s_waitcnt vmcnt(1)" ::: "memory");  // S(t) landed
        } else {
            asm volatile("s_waitcnt vmcnt(0)" ::: "memory");
        }
        __syncthreads();
        if (t + 2 < 64) {
            int nb = cur + 2; if (nb >= 3) nb -= 3;
            gld_lds16(sg + (size_t)(t + 2) * 2048, &lkv[nb][sl]);
        }

        const bf16* kl = &lkv[cur][laneoff];
        const bf16* vl = &lkv[cur][2048 + laneoff];
        bf16x8 kf0  = *(const bf16x8*)(kl);
        bf16x8 kf1  = *(const bf16x8*)(kl + 512);
        bf16x8 kf2  = *(const bf16x8*)(kl + 1024);
        bf16x8 kf3  = *(const bf16x8*)(kl + 1536);
        bf16x8 vf00 = *(const bf16x8*)(vl);
        bf16x8 vf01 = *(const bf16x8*)(vl + 512);
        bf16x8 vf10 = *(const bf16x8*)(vl + 1024);
        bf16x8 vf11 = *(const bf16x8*)(vl + 1536);

        f32x16 st = {};
        st = __builtin_amdgcn_mfma_f32_32x32x16_bf16(kf0, qf0, st, 0, 0, 0);
        st = __builtin_amdgcn_mfma_f32_32x32x16_bf16(kf1, qf1, st, 0, 0, 0);
        st = __builtin_amdgcn_mfma_f32_32x32x16_bf16(kf2, qf2, st, 0, 0, 0);
        st = __builtin_amdgcn_mfma_f32_32x32x16_bf16(kf3, qf3, st, 0, 0, 0);

#pragma unroll
        for (int r = 0; r < 16; ++r) st[r] = __builtin_amdgcn_exp2f(st[r]);

        float s0 = (st[0] + st[1]) + (st[2] + st[3]);
        float s1 = (st[4] + st[5]) + (st[6] + st[7]);
        float s2 = (st[8] + st[9]) + (st[10] + st[11]);
        float s3 = (st[12] + st[13]) + (st[14] + st[15]);
        lsum += (s0 + s1) + (s2 + s3);

        unsigned u01 = cvtpk(st[0],  st[1]),  u23 = cvtpk(st[2],  st[3]);
        unsigned u45 = cvtpk(st[4],  st[5]),  u67 = cvtpk(st[6],  st[7]);
        unsigned u89 = cvtpk(st[8],  st[9]),  uAB = cvtpk(st[10], st[11]);
        unsigned uCD = cvtpk(st[12], st[13]), uEF = cvtpk(st[14], st[15]);
        pswap(u01, u45); pswap(u23, u67);
        pswap(u89, uCD); pswap(uAB, uEF);
        union { unsigned u[4]; bf16x8 v; } pf0, pf1;
        pf0.u[0] = u01; pf0.u[1] = u23; pf0.u[2] = u45; pf0.u[3] = u67;
        pf1.u[0] = u89; pf1.u[1] = uAB; pf1.u[2] = uCD; pf1.u[3] = uEF;

        acc0 = __builtin_amdgcn_mfma_f32_32x32x16_bf16(vf00, pf0.v, acc0, 0, 0, 0);
        acc1 = __builtin_amdgcn_mfma_f32_32x32x16_bf16(vf10, pf0.v, acc1, 0, 0, 0);
        acc0 = __builtin_amdgcn_mfma_f32_32x32x16_bf16(vf01, pf1.v, acc0, 0, 0, 0);
        acc1 = __builtin_amdgcn_mfma_f32_32x32x16_bf16(vf11, pf1.v, acc1, 0, 0, 0);

        cur = (cur == 2) ? 0 : cur + 1;
    }

    lsum += __shfl_xor(lsum, 32);
    float inv = 1.0f / lsum;
    int qg = q0 + l31;
    bf16* ob = O + ((size_t)(bh >> 4) * 2048 + qg) * 1024 + (size_t)(bh & 15) * 64;
#pragma unroll
    for (int rg = 0; rg < 4; ++rg) {
        bf16x4 w0, w1;
#pragma unroll
        for (int i = 0; i < 4; ++i) {
            w0[i] = (bf16)(acc0[rg * 4 + i] * inv);
            w1[i] = (bf16)(acc1[rg * 4 + i] * inv);
        }
        *(bf16x4*)(ob + 8 * rg + 4 * hi)      = w0;
        *(bf16x4*)(ob + 32 + 8 * rg + 4 * hi) = w1;
    }
}

extern "C" void kernel_launch(void* const* d_in, const int* in_sizes, int n_in,
                              void* d_out, int out_size, void* d_ws, size_t ws_size,
                              hipStream_t stream) {
    (void)in_sizes; (void)n_in; (void)out_size; (void)ws_size;
    // setup_inputs order: V, K, Q, Wv, bv, Wk, bk, Wq, bq, Wo, bo
    const float* V  = (const float*)d_in[0];
    const float* K  = (const float*)d_in[1];
    const float* Q  = (const float*)d_in[2];
    const float* Wv = (const float*)d_in[3];
    const float* bv = (const float*)d_in[4];
    const float* Wk = (const float*)d_in[5];
    const float* bk = (const float*)d_in[6];
    const float* Wq = (const float*)d_in[7];
    const float* bq = (const float*)d_in[8];
    const float* Wo = (const float*)d_in[9];
    const float* bo = (const float*)d_in[10];

    char* ws = (char*)d_ws;
    const size_t MB = 1ull << 20;
    bf16* Xq  = (bf16*)(ws + 0);        // dead after proj -> reused as O
    bf16* Xk  = (bf16*)(ws + 16 * MB);
    bf16* Xv  = (bf16*)(ws + 32 * MB);
    bf16* Wqb = (bf16*)(ws + 48 * MB);
    bf16* Wkb = (bf16*)(ws + 50 * MB);
    bf16* Wvb = (bf16*)(ws + 52 * MB);
    bf16* Wob = (bf16*)(ws + 54 * MB);
    bf16* qw  = (bf16*)(ws + 56 * MB);
    bf16* kw  = (bf16*)(ws + 72 * MB);
    bf16* vtw = (bf16*)(ws + 88 * MB);
    bf16* Ow  = (bf16*)(ws + 0);

    cvt_all<<<14336, 256, 0, stream>>>(Q, K, V, Wq, Wk, Wv, Wo, (bf16*)ws);

    proj_fused<<<dim3(8, 64, 3), 256, 0, stream>>>(
        Xq, Xk, Xv, Wqb, Wkb, Wvb, bq, bk, bv, qw, kw, vtw);

    attn_kernel<<<512, 512, 0, stream>>>(qw, kw, vtw, Ow);

    gemm_out<<<dim3(8, 64), 256, 0, stream>>>(Ow, Wob, bo, (float*)d_out);
}